// Round 1
// baseline (11053.841 us; speedup 1.0000x reference)
//
#include <hip/hip_runtime.h>

#define B_ 8
#define T_ 32000
#define RES_ 64
#define TT 62            // output columns per block
#define GT 64            // staged/gated columns per block = TT+2
#define NBT ((T_ + TT - 1) / TT)   // 517

__device__ __forceinline__ float ftanh(float x) {
    return 1.0f - 2.0f / (1.0f + __expf(2.0f * x));
}
__device__ __forceinline__ float fsig(float x) {
    return 1.0f / (1.0f + __expf(-x));
}

// transpose [L][OC][IC][3] -> [L][3][IC][OC]
__global__ void k_tr(const float* __restrict__ src, float* __restrict__ dst,
                     int L, int OC, int IC) {
    int n = L * OC * IC * 3;
    int idx = blockIdx.x * 256 + threadIdx.x;
    if (idx >= n) return;
    int j = idx % 3;
    int ic = (idx / 3) % IC;
    int oc = (idx / (3 * IC)) % OC;
    int l = idx / (3 * IC * OC);
    dst[((l * 3 + j) * IC + ic) * OC + oc] = src[idx];
}

// h = cconv(x, w_in), x: [B][1][T], w_in: [RES][1][3]
__global__ void k_in(const float* __restrict__ x, const float* __restrict__ w_in,
                     float* __restrict__ h) {
    int t = blockIdx.x * 256 + threadIdx.x;
    int c = blockIdx.y, b = blockIdx.z;
    const float* xb = x + b * T_;
    float w0 = w_in[c * 3], w1 = w_in[c * 3 + 1], w2 = w_in[c * 3 + 2];
    float acc = w2 * xb[t];
    if (t >= 1) acc += w1 * xb[t - 1];
    if (t >= 2) acc += w0 * xb[t - 2];
    h[(b * RES_ + c) * T_ + t] = acc;
}

// One fused residual layer.
// g = cconv_d(h, w_res); gated = tanh(g[:64])*sig(g[64:]);
// o = cconv_1(gated, w_skip); hout = hin + o[:64]; skip (+)= o[64:]
template <int ACC>
__global__ __launch_bounds__(512, 4)
void k_layer(const float* __restrict__ hin, float* __restrict__ hout,
             float* __restrict__ skip,
             const float* __restrict__ wresT,   // [3][64][128]
             const float* __restrict__ wskipT,  // [3][64][128]
             int d) {
    // 80 KB LDS: sH[3][64][64] (48K) | sW[64][128] (32K); sG[64][64] aliases sH.
    __shared__ __align__(16) float smem[20480];
    float (*sH)[RES_][GT] = (float (*)[RES_][GT])smem;            // 12288 floats
    float (*sW)[128]      = (float (*)[128])(smem + 12288);       // 8192 floats
    float (*sG)[GT]       = (float (*)[GT])smem;                  // 4096 floats (alias)

    const int tid  = threadIdx.x;
    const int lane = tid & 63;
    const int wave = tid >> 6;
    const int oc0  = wave * 16;           // 8 waves x 16 oc = 128
    const int b    = blockIdx.y;
    const int t0   = blockIdx.x * TT;

    // stage 3 shifted input tiles: col <-> t = t0 - 2 + col - d*(2-j)
    const float* hb = hin + b * RES_ * T_;
    for (int idx = tid; idx < 3 * RES_ * GT; idx += 512) {
        int col = idx & 63;
        int ic  = (idx >> 6) & 63;
        int j   = idx >> 12;
        int t   = t0 - 2 + col - d * (2 - j);
        float v = 0.f;
        if (t >= 0 && t < T_) v = hb[ic * T_ + t];
        sH[j][ic][col] = v;
    }

    float acc[16];
#pragma unroll
    for (int k = 0; k < 16; ++k) acc[k] = 0.f;

    // ---- res conv (dilated): G[oc][col] ----
    for (int j = 0; j < 3; ++j) {
        __syncthreads();                       // sH staged / prev sW consumed
        for (int idx = tid; idx < RES_ * 128; idx += 512)
            ((float*)sW)[idx] = wresT[j * RES_ * 128 + idx];
        __syncthreads();
#pragma unroll 4
        for (int ic = 0; ic < RES_; ++ic) {
            float hv = sH[j][ic][lane];
            const float* wr = &sW[ic][oc0];
#pragma unroll
            for (int k = 0; k < 16; ++k) acc[k] += hv * wr[k];
        }
    }
    __syncthreads();   // all sH/sW reads done; sG may now overwrite sH

    // ---- gating into sG[64][GT] ----
    if (wave < 4) {
#pragma unroll
        for (int k = 0; k < 16; ++k) sG[oc0 + k][lane] = ftanh(acc[k]);
    }
    __syncthreads();
    if (wave >= 4) {
        int c0 = oc0 - 64;
#pragma unroll
        for (int k = 0; k < 16; ++k) sG[c0 + k][lane] *= fsig(acc[k]);
    }

    // ---- skip conv (dilation 1): O[oc][to], to = lane (valid < TT) ----
    float a2[16];
#pragma unroll
    for (int k = 0; k < 16; ++k) a2[k] = 0.f;

    for (int j = 0; j < 3; ++j) {
        __syncthreads();                       // gated visible / prev sW consumed
        for (int idx = tid; idx < RES_ * 128; idx += 512)
            ((float*)sW)[idx] = wskipT[j * RES_ * 128 + idx];
        __syncthreads();
        int cs = lane + j; if (cs > 63) cs = 63;   // clamped only for masked lanes
#pragma unroll 4
        for (int ic = 0; ic < RES_; ++ic) {
            float gv = sG[ic][cs];
            const float* wr = &sW[ic][oc0];
#pragma unroll
            for (int k = 0; k < 16; ++k) a2[k] += gv * wr[k];
        }
    }

    int t = t0 + lane;
    if (lane < TT && t < T_) {
        if (wave < 4) {
#pragma unroll
            for (int k = 0; k < 16; ++k) {
                int off = (b * RES_ + oc0 + k) * T_ + t;
                hout[off] = hin[off] + a2[k];
            }
        } else {
#pragma unroll
            for (int k = 0; k < 16; ++k) {
                int off = (b * RES_ + oc0 - 64 + k) * T_ + t;
                skip[off] = (ACC ? skip[off] : 0.f) + a2[k];
            }
        }
    }
}

// 64->64 conv k=3 d=1, optional tanh on input read, tanh on output
template <int INTANH>
__global__ __launch_bounds__(512, 4)
void k_conv64(const float* __restrict__ in, float* __restrict__ out,
              const float* __restrict__ wT /* [3][64][64] */) {
    __shared__ __align__(16) float sIn[RES_][GT];        // 16 KB
    __shared__ __align__(16) float sWc[3][RES_][RES_];   // 48 KB
    const int tid  = threadIdx.x;
    const int lane = tid & 63;
    const int wave = tid >> 6;
    const int oc0  = wave * 8;           // 8 waves x 8 oc = 64
    const int b    = blockIdx.y;
    const int t0   = blockIdx.x * TT;

    for (int idx = tid; idx < 3 * RES_ * RES_; idx += 512)
        ((float*)sWc)[idx] = wT[idx];
    const float* ib = in + b * RES_ * T_;
    for (int idx = tid; idx < RES_ * GT; idx += 512) {
        int col = idx & 63;
        int ic  = idx >> 6;
        int t   = t0 - 2 + col;
        float v = (t >= 0 && t < T_) ? ib[ic * T_ + t] : 0.f;
        if (INTANH) v = ftanh(v);
        sIn[ic][col] = v;
    }
    __syncthreads();

    float acc[8];
#pragma unroll
    for (int k = 0; k < 8; ++k) acc[k] = 0.f;
    for (int j = 0; j < 3; ++j) {
        int cs = lane + j; if (cs > 63) cs = 63;
#pragma unroll 4
        for (int ic = 0; ic < RES_; ++ic) {
            float gv = sIn[ic][cs];
            const float* wr = &sWc[j][ic][oc0];
#pragma unroll
            for (int k = 0; k < 8; ++k) acc[k] += gv * wr[k];
        }
    }
    int t = t0 + lane;
    if (lane < TT && t < T_) {
#pragma unroll
        for (int k = 0; k < 8; ++k)
            out[(b * RES_ + oc0 + k) * T_ + t] = ftanh(acc[k]);
    }
}

// y = tanh(cconv(in, w4)), 64 -> 1 channel
__global__ void k_last(const float* __restrict__ in, const float* __restrict__ w4,
                       float* __restrict__ y) {
    int t = blockIdx.x * 256 + threadIdx.x;
    int b = blockIdx.y;
    const float* ib = in + b * RES_ * T_;
    float acc = 0.f;
    for (int ic = 0; ic < RES_; ++ic) {
        const float* r = ib + ic * T_;
        float s = w4[ic * 3 + 2] * r[t];
        if (t >= 1) s += w4[ic * 3 + 1] * r[t - 1];
        if (t >= 2) s += w4[ic * 3 + 0] * r[t - 2];
        acc += s;
    }
    y[b * T_ + t] = ftanh(acc);
}

// VNN2: lin = cconv(y, vw1) k=5; x2 = cconv(y, vw2) (6 ch); out = lin + sum_q x2[q]*x2[q+3]
__global__ void k_vnn(const float* __restrict__ y, const float* __restrict__ vw1,
                      const float* __restrict__ vw2, float* __restrict__ out) {
    int t = blockIdx.x * 256 + threadIdx.x;
    int b = blockIdx.y;
    const float* yb = y + b * T_;
    float v[5];
#pragma unroll
    for (int j = 0; j < 5; ++j) {
        int tt = t - 4 + j;
        v[j] = (tt >= 0) ? yb[tt] : 0.f;
    }
    float lin = 0.f;
#pragma unroll
    for (int j = 0; j < 5; ++j) lin += v[j] * vw1[j];
    float xa[6];
#pragma unroll
    for (int c = 0; c < 6; ++c) {
        float s = 0.f;
#pragma unroll
        for (int j = 0; j < 5; ++j) s += v[j] * vw2[c * 5 + j];
        xa[c] = s;
    }
    out[b * T_ + t] = lin + xa[0] * xa[3] + xa[1] * xa[4] + xa[2] * xa[5];
}

extern "C" void kernel_launch(void* const* d_in, const int* in_sizes, int n_in,
                              void* d_out, int out_size, void* d_ws, size_t ws_size,
                              hipStream_t stream) {
    const float* x      = (const float*)d_in[0];
    const float* w_in   = (const float*)d_in[1];
    const float* w_res  = (const float*)d_in[2];
    const float* w_skip = (const float*)d_in[3];
    const float* w2     = (const float*)d_in[4];
    const float* w3     = (const float*)d_in[5];
    const float* w4     = (const float*)d_in[6];
    const float* vw1    = (const float*)d_in[7];
    const float* vw2    = (const float*)d_in[8];

    float* ws     = (float*)d_ws;
    const size_t HSZ = (size_t)B_ * RES_ * T_;   // 16,384,000
    float* hA     = ws;
    float* hB     = hA + HSZ;
    float* skip   = hB + HSZ;
    float* y      = skip + HSZ;                  // 256,000
    float* wresT  = y + (size_t)B_ * T_;         // 245,760
    float* wskipT = wresT + 10 * 3 * 64 * 128;   // 245,760
    float* w2T    = wskipT + 10 * 3 * 64 * 128;  // 12,288
    float* w3T    = w2T + 3 * 64 * 64;           // 12,288

    k_tr<<<dim3(960), 256, 0, stream>>>(w_res, wresT, 10, 128, 64);
    k_tr<<<dim3(960), 256, 0, stream>>>(w_skip, wskipT, 10, 128, 64);
    k_tr<<<dim3(48), 256, 0, stream>>>(w2, w2T, 1, 64, 64);
    k_tr<<<dim3(48), 256, 0, stream>>>(w3, w3T, 1, 64, 64);

    k_in<<<dim3(T_ / 256, RES_, B_), 256, 0, stream>>>(x, w_in, hA);

    float* cur = hA;
    float* nxt = hB;
    for (int li = 0; li < 20; ++li) {
        int i = li % 10;
        int d = 1 << i;
        const float* wr = wresT + i * 3 * 64 * 128;
        const float* wk = wskipT + i * 3 * 64 * 128;
        if (li == 0)
            k_layer<0><<<dim3(NBT, B_), 512, 0, stream>>>(cur, nxt, skip, wr, wk, d);
        else
            k_layer<1><<<dim3(NBT, B_), 512, 0, stream>>>(cur, nxt, skip, wr, wk, d);
        float* tmp = cur; cur = nxt; nxt = tmp;
    }

    // post-net: a = tanh(skip) -> conv w2 (tanh) -> conv w3 (tanh) -> w4 (tanh) -> VNN
    k_conv64<1><<<dim3(NBT, B_), 512, 0, stream>>>(skip, hA, w2T);
    k_conv64<0><<<dim3(NBT, B_), 512, 0, stream>>>(hA, hB, w3T);
    k_last<<<dim3(T_ / 256, B_), 256, 0, stream>>>(hB, w4, y);
    k_vnn<<<dim3(T_ / 256, B_), 256, 0, stream>>>(y, vw1, vw2, (float*)d_out);
}

// Round 2
// 4234.114 us; speedup vs baseline: 2.6107x; 2.6107x over previous
//
#include <hip/hip_runtime.h>

#define B_ 8
#define T_ 32000
#define RES_ 64
#define NSTEP 16
#define STRIP (16 * NSTEP)          // 256 cols per block
#define NSTRIP (T_ / STRIP)         // 125

typedef __attribute__((ext_vector_type(8))) short short8;
typedef __attribute__((ext_vector_type(4))) float f32x4;
typedef __attribute__((ext_vector_type(4))) unsigned u32x4;

#define MFMA(a, b, c) __builtin_amdgcn_mfma_f32_16x16x32_bf16(a, b, c, 0, 0, 0)

__device__ __forceinline__ float ftanh(float x) {
    return 1.0f - 2.0f / (1.0f + __expf(2.0f * x));
}
__device__ __forceinline__ float fsig(float x) {
    return 1.0f / (1.0f + __expf(-x));
}
__device__ __forceinline__ unsigned f2bf(float x) {   // RNE float->bf16 (bits)
    unsigned u = __float_as_uint(x);
    return (u + 0x7fffu + ((u >> 16) & 1u)) >> 16;
}
__device__ __forceinline__ float bf2f(unsigned h) { return __uint_as_float(h << 16); }
__device__ __forceinline__ void split2(float x, unsigned &h, unsigned &l) {
    h = f2bf(x);
    l = f2bf(x - bf2f(h));
}

// transpose [L][OC][IC][3] -> [L][3][IC][OC]
__global__ void k_tr(const float* __restrict__ src, float* __restrict__ dst,
                     int L, int OC, int IC) {
    int n = L * OC * IC * 3;
    int idx = blockIdx.x * 256 + threadIdx.x;
    if (idx >= n) return;
    int j = idx % 3;
    int ic = (idx / 3) % IC;
    int oc = (idx / (3 * IC)) % OC;
    int l = idx / (3 * IC * OC);
    dst[((l * 3 + j) * IC + ic) * OC + oc] = src[idx];
}

// h = cconv(x, w_in), x: [B][1][T], w_in: [RES][1][3]
__global__ void k_in(const float* __restrict__ x, const float* __restrict__ w_in,
                     float* __restrict__ h) {
    int t = blockIdx.x * 256 + threadIdx.x;
    int c = blockIdx.y, b = blockIdx.z;
    const float* xb = x + b * T_;
    float w0 = w_in[c * 3], w1 = w_in[c * 3 + 1], w2 = w_in[c * 3 + 2];
    float acc = w2 * xb[t];
    if (t >= 1) acc += w1 * xb[t - 1];
    if (t >= 2) acc += w0 * xb[t - 2];
    h[(b * RES_ + c) * T_ + t] = acc;
}

// ---------------- k1: dilated res-conv + gating -> gbuf (packed bf16 hi|lo) ----
// g[oc][t] = sum_{j,ic} Wres[j][ic][oc] * h[ic][t - d*(2-j)]
// gated[c][t] = tanh(g[c]) * sig(g[c+64]); stored as u32 (hi | lo<<16)
__global__ __launch_bounds__(256)
void k1(const float* __restrict__ hin, unsigned* __restrict__ gbuf,
        const float* __restrict__ wT /* [3][64][128] */, int d) {
    __shared__ __align__(16) unsigned short sHi[3 * 16 * 64];
    __shared__ __align__(16) unsigned short sLo[3 * 16 * 64];
    const int tid = threadIdx.x;
    const int lane = tid & 63;
    const int ocg = tid >> 6;        // 0..3
    const int cc = lane & 15;
    const int kb = lane >> 4;        // 0..3
    const int bb = blockIdx.y;
    const int tbase = blockIdx.x * STRIP;
    const float* hb = hin + (size_t)bb * RES_ * T_;

    const int cA = 16 * ocg + cc;    // tanh-side channel
    const int cB = 64 + cA;          // sigmoid-side channel
    short8 whA[6], wlA[6], whB[6], wlB[6];
#pragma unroll
    for (int q = 0; q < 6; ++q) {
        const int j = q >> 1, icb = (q & 1) * 32 + kb * 8;
        const float* wp = wT + (j * 64 + icb) * 128;
#pragma unroll
        for (int jj = 0; jj < 8; ++jj) {
            unsigned h, l;
            split2(wp[jj * 128 + cA], h, l);
            whA[q][jj] = (short)h; wlA[q][jj] = (short)l;
            split2(wp[jj * 128 + cB], h, l);
            whB[q][jj] = (short)h; wlB[q][jj] = (short)l;
        }
    }

    for (int step = 0; step < NSTEP; ++step) {
        const int t0 = tbase + step * 16;
        // stage 3 shifted tap tiles, bf16 hi/lo, XOR-swizzled, pair-packed writes
#pragma unroll
        for (int it = 0; it < 6; ++it) {
            int idx = it * 256 + tid;          // < 1536 = 3*16*32
            int j = idx >> 9;                  // /512
            int r = idx & 511;
            int icp = r >> 4;                  // ic pair 0..31
            int c = r & 15;
            int t = t0 + c - d * (2 - j);
            float v0 = 0.f, v1 = 0.f;
            if (t >= 0) {
                v0 = hb[(2 * icp) * T_ + t];
                v1 = hb[(2 * icp + 1) * T_ + t];
            }
            unsigned h0, l0, h1, l1;
            split2(v0, h0, l0);
            split2(v1, h1, l1);
            int w = j * 512 + c * 32 + (icp ^ ((c & 7) * 4));
            ((unsigned*)sHi)[w] = h0 | (h1 << 16);
            ((unsigned*)sLo)[w] = l0 | (l1 << 16);
        }
        __syncthreads();

        f32x4 accA = {0.f, 0.f, 0.f, 0.f}, accB = {0.f, 0.f, 0.f, 0.f};
#pragma unroll
        for (int q = 0; q < 6; ++q) {
            const int j = q >> 1;
            const int ic0 = (q & 1) * 32 + kb * 8;
            const int us = j * 1024 + cc * 64 + (ic0 ^ ((cc & 7) * 8));
            short8 ah = *(const short8*)(sHi + us);
            short8 al = *(const short8*)(sLo + us);
            accA = MFMA(ah, whA[q], accA);
            accA = MFMA(al, whA[q], accA);
            accA = MFMA(ah, wlA[q], accA);
            accB = MFMA(ah, whB[q], accB);
            accB = MFMA(al, whB[q], accB);
            accB = MFMA(ah, wlB[q], accB);
        }
        __syncthreads();

        // gating + packed store (D: col=lane&15 -> oc, row=(lane>>4)*4+r -> t)
        u32x4 pk;
#pragma unroll
        for (int r = 0; r < 4; ++r) {
            float gv = ftanh(accA[r]) * fsig(accB[r]);
            unsigned h, l;
            split2(gv, h, l);
            pk[r] = h | (l << 16);
        }
        const int trow = t0 + kb * 4;
        *(u32x4*)(gbuf + (size_t)(bb * 64 + cA) * T_ + trow) = pk;
    }
}

// ---------------- k2: d=1 skip-conv + residual + skip accumulate ---------------
// o[oc][t] = sum_{j,ic} Wsk[j][ic][oc] * gated[ic][t-2+j]
template <int ACC>
__global__ __launch_bounds__(256)
void k2(const unsigned* __restrict__ gbuf, const float* __restrict__ hin,
        float* __restrict__ hout, float* __restrict__ skip,
        const float* __restrict__ wT /* [3][64][128] */) {
    __shared__ __align__(16) unsigned short sHi[18 * 64];
    __shared__ __align__(16) unsigned short sLo[18 * 64];
    const int tid = threadIdx.x;
    const int lane = tid & 63;
    const int ocg = tid >> 6;
    const int cc = lane & 15;
    const int kb = lane >> 4;
    const int bb = blockIdx.y;
    const int tbase = blockIdx.x * STRIP;
    const unsigned* gb = gbuf + (size_t)bb * 64 * T_;

    const int oc0 = 32 * ocg + cc;
    const int oc1 = oc0 + 16;
    short8 whA[6], wlA[6], whB[6], wlB[6];
#pragma unroll
    for (int q = 0; q < 6; ++q) {
        const int j = q >> 1, icb = (q & 1) * 32 + kb * 8;
        const float* wp = wT + (j * 64 + icb) * 128;
#pragma unroll
        for (int jj = 0; jj < 8; ++jj) {
            unsigned h, l;
            split2(wp[jj * 128 + oc0], h, l);
            whA[q][jj] = (short)h; wlA[q][jj] = (short)l;
            split2(wp[jj * 128 + oc1], h, l);
            whB[q][jj] = (short)h; wlB[q][jj] = (short)l;
        }
    }

    for (int step = 0; step < NSTEP; ++step) {
        const int t0 = tbase + step * 16;
        // stage gated cols [t0-2, t0+16) (18 cols), unpack hi/lo, swizzled
#pragma unroll
        for (int it = 0; it < 3; ++it) {
            int idx = it * 256 + tid;
            if (idx < 576) {                   // 32 pairs * 18 cols
                int ic2 = idx / 18;
                int c = idx - ic2 * 18;
                int t = t0 - 2 + c;
                unsigned v0 = 0u, v1 = 0u;
                if (t >= 0) {
                    v0 = gb[(2 * ic2) * T_ + t];
                    v1 = gb[(2 * ic2 + 1) * T_ + t];
                }
                int w = c * 32 + (ic2 ^ ((c & 7) * 4));
                ((unsigned*)sHi)[w] = (v0 & 0xffffu) | (v1 << 16);
                ((unsigned*)sLo)[w] = (v0 >> 16) | (v1 & 0xffff0000u);
            }
        }
        __syncthreads();

        f32x4 accA = {0.f, 0.f, 0.f, 0.f}, accB = {0.f, 0.f, 0.f, 0.f};
#pragma unroll
        for (int q = 0; q < 6; ++q) {
            const int j = q >> 1;
            const int ic0 = (q & 1) * 32 + kb * 8;
            const int c = cc + j;
            const int us = c * 64 + (ic0 ^ ((c & 7) * 8));
            short8 ah = *(const short8*)(sHi + us);
            short8 al = *(const short8*)(sLo + us);
            accA = MFMA(ah, whA[q], accA);
            accA = MFMA(al, whA[q], accA);
            accA = MFMA(ah, wlA[q], accA);
            accB = MFMA(ah, whB[q], accB);
            accB = MFMA(al, whB[q], accB);
            accB = MFMA(ah, wlB[q], accB);
        }
        __syncthreads();

        const int trow = t0 + kb * 4;
        {
            // tile0
            if (oc0 < 64) {
                size_t off = ((size_t)bb * 64 + oc0) * T_ + trow;
                f32x4 h0 = *(const f32x4*)(hin + off);
                *(f32x4*)(hout + off) = h0 + accA;
            } else {
                size_t off = ((size_t)bb * 64 + (oc0 - 64)) * T_ + trow;
                f32x4 s = ACC ? *(const f32x4*)(skip + off) : (f32x4){0.f, 0.f, 0.f, 0.f};
                *(f32x4*)(skip + off) = s + accA;
            }
            // tile1
            if (oc1 < 64) {
                size_t off = ((size_t)bb * 64 + oc1) * T_ + trow;
                f32x4 h0 = *(const f32x4*)(hin + off);
                *(f32x4*)(hout + off) = h0 + accB;
            } else {
                size_t off = ((size_t)bb * 64 + (oc1 - 64)) * T_ + trow;
                f32x4 s = ACC ? *(const f32x4*)(skip + off) : (f32x4){0.f, 0.f, 0.f, 0.f};
                *(f32x4*)(skip + off) = s + accB;
            }
        }
    }
}

// ---------------- post-net 64->64 conv (k=3,d=1), optional tanh in, tanh out ---
template <int INTANH>
__global__ __launch_bounds__(256)
void k_post(const float* __restrict__ in, float* __restrict__ out,
            const float* __restrict__ wT /* [3][64][64] */) {
    __shared__ __align__(16) unsigned short sHi[18 * 64];
    __shared__ __align__(16) unsigned short sLo[18 * 64];
    const int tid = threadIdx.x;
    const int lane = tid & 63;
    const int ocg = tid >> 6;
    const int cc = lane & 15;
    const int kb = lane >> 4;
    const int bb = blockIdx.y;
    const int tbase = blockIdx.x * STRIP;
    const float* ib = in + (size_t)bb * 64 * T_;

    const int oc = 16 * ocg + cc;
    short8 wh[6], wl[6];
#pragma unroll
    for (int q = 0; q < 6; ++q) {
        const int j = q >> 1, icb = (q & 1) * 32 + kb * 8;
        const float* wp = wT + (j * 64 + icb) * 64;
#pragma unroll
        for (int jj = 0; jj < 8; ++jj) {
            unsigned h, l;
            split2(wp[jj * 64 + oc], h, l);
            wh[q][jj] = (short)h; wl[q][jj] = (short)l;
        }
    }

    for (int step = 0; step < NSTEP; ++step) {
        const int t0 = tbase + step * 16;
#pragma unroll
        for (int it = 0; it < 3; ++it) {
            int idx = it * 256 + tid;
            if (idx < 576) {
                int ic2 = idx / 18;
                int c = idx - ic2 * 18;
                int t = t0 - 2 + c;
                float v0 = 0.f, v1 = 0.f;
                if (t >= 0) {
                    v0 = ib[(2 * ic2) * T_ + t];
                    v1 = ib[(2 * ic2 + 1) * T_ + t];
                }
                if (INTANH) { v0 = ftanh(v0); v1 = ftanh(v1); }
                unsigned h0, l0, h1, l1;
                split2(v0, h0, l0);
                split2(v1, h1, l1);
                int w = c * 32 + (ic2 ^ ((c & 7) * 4));
                ((unsigned*)sHi)[w] = h0 | (h1 << 16);
                ((unsigned*)sLo)[w] = l0 | (l1 << 16);
            }
        }
        __syncthreads();

        f32x4 acc = {0.f, 0.f, 0.f, 0.f};
#pragma unroll
        for (int q = 0; q < 6; ++q) {
            const int j = q >> 1;
            const int ic0 = (q & 1) * 32 + kb * 8;
            const int c = cc + j;
            const int us = c * 64 + (ic0 ^ ((c & 7) * 8));
            short8 ah = *(const short8*)(sHi + us);
            short8 al = *(const short8*)(sLo + us);
            acc = MFMA(ah, wh[q], acc);
            acc = MFMA(al, wh[q], acc);
            acc = MFMA(ah, wl[q], acc);
        }
        __syncthreads();

        const int trow = t0 + kb * 4;
        f32x4 o;
#pragma unroll
        for (int r = 0; r < 4; ++r) o[r] = ftanh(acc[r]);
        *(f32x4*)(out + ((size_t)bb * 64 + oc) * T_ + trow) = o;
    }
}

// y = tanh(cconv(in, w4)), 64 -> 1 channel
__global__ void k_last(const float* __restrict__ in, const float* __restrict__ w4,
                       float* __restrict__ y) {
    int t = blockIdx.x * 256 + threadIdx.x;
    int b = blockIdx.y;
    const float* ib = in + (size_t)b * RES_ * T_;
    float acc = 0.f;
    for (int ic = 0; ic < RES_; ++ic) {
        const float* r = ib + ic * T_;
        float s = w4[ic * 3 + 2] * r[t];
        if (t >= 1) s += w4[ic * 3 + 1] * r[t - 1];
        if (t >= 2) s += w4[ic * 3 + 0] * r[t - 2];
        acc += s;
    }
    y[b * T_ + t] = ftanh(acc);
}

// VNN2
__global__ void k_vnn(const float* __restrict__ y, const float* __restrict__ vw1,
                      const float* __restrict__ vw2, float* __restrict__ out) {
    int t = blockIdx.x * 256 + threadIdx.x;
    int b = blockIdx.y;
    const float* yb = y + b * T_;
    float v[5];
#pragma unroll
    for (int j = 0; j < 5; ++j) {
        int tt = t - 4 + j;
        v[j] = (tt >= 0) ? yb[tt] : 0.f;
    }
    float lin = 0.f;
#pragma unroll
    for (int j = 0; j < 5; ++j) lin += v[j] * vw1[j];
    float xa[6];
#pragma unroll
    for (int c = 0; c < 6; ++c) {
        float s = 0.f;
#pragma unroll
        for (int j = 0; j < 5; ++j) s += v[j] * vw2[c * 5 + j];
        xa[c] = s;
    }
    out[b * T_ + t] = lin + xa[0] * xa[3] + xa[1] * xa[4] + xa[2] * xa[5];
}

extern "C" void kernel_launch(void* const* d_in, const int* in_sizes, int n_in,
                              void* d_out, int out_size, void* d_ws, size_t ws_size,
                              hipStream_t stream) {
    const float* x      = (const float*)d_in[0];
    const float* w_in   = (const float*)d_in[1];
    const float* w_res  = (const float*)d_in[2];
    const float* w_skip = (const float*)d_in[3];
    const float* w2     = (const float*)d_in[4];
    const float* w3     = (const float*)d_in[5];
    const float* w4     = (const float*)d_in[6];
    const float* vw1    = (const float*)d_in[7];
    const float* vw2    = (const float*)d_in[8];

    float* ws = (float*)d_ws;
    const size_t HSZ = (size_t)B_ * RES_ * T_;   // 16,384,000
    float*    hA     = ws;
    float*    hB     = hA + HSZ;
    float*    skip   = hB + HSZ;
    unsigned* gbuf   = (unsigned*)(skip + HSZ);
    float*    y      = (float*)(gbuf + HSZ);
    float*    wresT  = y + (size_t)B_ * T_;
    float*    wskipT = wresT + 10 * 3 * 64 * 128;
    float*    w2T    = wskipT + 10 * 3 * 64 * 128;
    float*    w3T    = w2T + 3 * 64 * 64;

    k_tr<<<dim3(960), 256, 0, stream>>>(w_res, wresT, 10, 128, 64);
    k_tr<<<dim3(960), 256, 0, stream>>>(w_skip, wskipT, 10, 128, 64);
    k_tr<<<dim3(48), 256, 0, stream>>>(w2, w2T, 1, 64, 64);
    k_tr<<<dim3(48), 256, 0, stream>>>(w3, w3T, 1, 64, 64);

    k_in<<<dim3(T_ / 256, RES_, B_), 256, 0, stream>>>(x, w_in, hA);

    float* cur = hA;
    float* nxt = hB;
    for (int li = 0; li < 20; ++li) {
        int i = li % 10;
        int d = 1 << i;
        k1<<<dim3(NSTRIP, B_), 256, 0, stream>>>(cur, gbuf, wresT + i * 3 * 64 * 128, d);
        if (li == 0)
            k2<0><<<dim3(NSTRIP, B_), 256, 0, stream>>>(gbuf, cur, nxt, skip,
                                                        wskipT + i * 3 * 64 * 128);
        else
            k2<1><<<dim3(NSTRIP, B_), 256, 0, stream>>>(gbuf, cur, nxt, skip,
                                                        wskipT + i * 3 * 64 * 128);
        float* tmp = cur; cur = nxt; nxt = tmp;
    }

    // post-net: tanh(skip) -> conv w2 (tanh) -> conv w3 (tanh) -> w4 (tanh) -> VNN
    k_post<1><<<dim3(NSTRIP, B_), 256, 0, stream>>>(skip, hB, w2T);
    k_post<0><<<dim3(NSTRIP, B_), 256, 0, stream>>>(hB, hA, w3T);
    k_last<<<dim3(T_ / 256, B_), 256, 0, stream>>>(hA, w4, y);
    k_vnn<<<dim3(T_ / 256, B_), 256, 0, stream>>>(y, vw1, vw2, (float*)d_out);
}

// Round 3
// 2987.568 us; speedup vs baseline: 3.6999x; 1.4172x over previous
//
#include <hip/hip_runtime.h>

#define B_ 8
#define T_ 32000
#define NSTEP 16
#define STRIP 256
#define NSTRIP 125

typedef __attribute__((ext_vector_type(8))) short short8;
typedef __attribute__((ext_vector_type(4))) float f32x4;
typedef __attribute__((ext_vector_type(4))) unsigned u32x4;

#define MFMA(a, b, c) __builtin_amdgcn_mfma_f32_16x16x32_bf16(a, b, c, 0, 0, 0)

__device__ __forceinline__ float ftanh(float x) {
    return 1.0f - 2.0f / (1.0f + __expf(2.0f * x));
}
__device__ __forceinline__ float fsig(float x) {
    return 1.0f / (1.0f + __expf(-x));
}
__device__ __forceinline__ unsigned f2bf(float x) {   // RNE float->bf16 (bits)
    unsigned u = __float_as_uint(x);
    return (u + 0x7fffu + ((u >> 16) & 1u)) >> 16;
}
__device__ __forceinline__ float bf2f(unsigned h) { return __uint_as_float(h << 16); }
__device__ __forceinline__ void split2(float x, unsigned &h, unsigned &l) {
    h = f2bf(x);
    l = f2bf(x - bf2f(h));
}
__device__ __forceinline__ unsigned packf(float x) {
    unsigned h, l;
    split2(x, h, l);
    return h | (l << 16);
}
__device__ __forceinline__ float unpf(unsigned v) {
    return bf2f(v & 0xffffu) + bf2f(v >> 16);
}

// transpose [L][OC][IC][3] -> [L][3][IC][OC]
__global__ void k_tr(const float* __restrict__ src, float* __restrict__ dst,
                     int L, int OC, int IC) {
    int n = L * OC * IC * 3;
    int idx = blockIdx.x * 256 + threadIdx.x;
    if (idx >= n) return;
    int j = idx % 3;
    int ic = (idx / 3) % IC;
    int oc = (idx / (3 * IC)) % OC;
    int l = idx / (3 * IC * OC);
    dst[((l * 3 + j) * IC + ic) * OC + oc] = src[idx];
}

// h = cconv(x, w_in) -> packed bf16-pair u32
__global__ void k_in(const float* __restrict__ x, const float* __restrict__ w_in,
                     unsigned* __restrict__ h) {
    int t = blockIdx.x * 256 + threadIdx.x;
    int c = blockIdx.y, b = blockIdx.z;
    const float* xb = x + b * T_;
    float w0 = w_in[c * 3], w1 = w_in[c * 3 + 1], w2 = w_in[c * 3 + 2];
    float acc = w2 * xb[t];
    if (t >= 1) acc += w1 * xb[t - 1];
    if (t >= 2) acc += w0 * xb[t - 2];
    h[(b * 64 + c) * T_ + t] = packf(acc);
}

// ---------------- fused residual layer (two-pass over a 256-col strip) --------
// pass A: g = cconv_d(h, wres); gated = tanh*sig -> LDS (258 cols, 2-col halo)
// pass B: o = cconv_1(gated, wskip); hout = hin + o[:64] (packed); skip += o[64:]
template <int ACC>
__global__ __launch_bounds__(256)
void k_layer(const unsigned* __restrict__ hin, unsigned* __restrict__ hout,
             float* __restrict__ skip,
             const float* __restrict__ wrT,   // [3][64][128]
             const float* __restrict__ wkT,   // [3][64][128]
             int d) {
    __shared__ __align__(16) unsigned sH_hi[3 * 512];        // [j][c16][icp32 swz]
    __shared__ __align__(16) unsigned sH_lo[3 * 512];
    __shared__ __align__(16) unsigned short sG_hi[258 * 64]; // [gc][ic swz]
    __shared__ __align__(16) unsigned short sG_lo[258 * 64];

    const int tid = threadIdx.x;
    const int lane = tid & 63;
    const int ocg = tid >> 6;        // 0..3
    const int cc = lane & 15;
    const int kb = lane >> 4;        // 0..3
    const int bb = blockIdx.y;
    const int tbase = blockIdx.x * STRIP;
    const unsigned* hb = hin + (size_t)bb * 64 * T_;

    short8 whA[6], wlA[6], whB[6], wlB[6];

    // ---- conv1 weights: wave computes g-channels cA (tanh) and cA+64 (sig) ----
    {
        const int cA = 16 * ocg + cc, cB = cA + 64;
#pragma unroll
        for (int q = 0; q < 6; ++q) {
            const int j = q >> 1, icb = (q & 1) * 32 + kb * 8;
            const float* wp = wrT + (j * 64 + icb) * 128;
#pragma unroll
            for (int jj = 0; jj < 8; ++jj) {
                unsigned h, l;
                split2(wp[jj * 128 + cA], h, l);
                whA[q][jj] = (short)h; wlA[q][jj] = (short)l;
                split2(wp[jj * 128 + cB], h, l);
                whB[q][jj] = (short)h; wlB[q][jj] = (short)l;
            }
        }
    }

    // ---- pass A: 17 steps (step -1 fills the 2-col halo) ----
    for (int s = -1; s < NSTEP; ++s) {
        const int t0 = tbase + s * 16;
        // stage 3 dilated tap tiles from packed global (cheap: no split2)
#pragma unroll
        for (int it = 0; it < 6; ++it) {
            int idx = it * 256 + tid;          // < 1536
            int j = idx >> 9;
            int r = idx & 511;
            int icp = r >> 4;                  // channel pair 0..31
            int c = r & 15;
            int t = t0 + c - d * (2 - j);
            unsigned v0 = 0u, v1 = 0u;
            if (t >= 0) {
                v0 = hb[(2 * icp) * T_ + t];
                v1 = hb[(2 * icp + 1) * T_ + t];
            }
            int w = j * 512 + c * 32 + (icp ^ ((c & 7) * 4));
            sH_hi[w] = (v0 & 0xffffu) | (v1 << 16);
            sH_lo[w] = (v0 >> 16) | (v1 & 0xffff0000u);
        }
        __syncthreads();

        f32x4 accA = {0.f, 0.f, 0.f, 0.f}, accB = {0.f, 0.f, 0.f, 0.f};
#pragma unroll
        for (int q = 0; q < 6; ++q) {
            const int j = q >> 1;
            const int ic0 = (q & 1) * 32 + kb * 8;
            const int us = j * 1024 + cc * 64 + (ic0 ^ ((cc & 7) * 8));
            short8 ah = *(const short8*)((const unsigned short*)sH_hi + us);
            short8 al = *(const short8*)((const unsigned short*)sH_lo + us);
            accA = MFMA(ah, whA[q], accA);
            accA = MFMA(al, whA[q], accA);
            accA = MFMA(ah, wlA[q], accA);
            accB = MFMA(ah, whB[q], accB);
            accB = MFMA(al, whB[q], accB);
            accB = MFMA(ah, wlB[q], accB);
        }

        // gate + write into persistent gated tile
        const int cA = 16 * ocg + cc;
#pragma unroll
        for (int r = 0; r < 4; ++r) {
            int gc = s * 16 + kb * 4 + r + 2;
            if (gc >= 0) {
                float gv = ftanh(accA[r]) * fsig(accB[r]);
                unsigned h, l;
                split2(gv, h, l);
                int a = gc * 64 + (cA ^ ((gc & 7) * 8));
                sG_hi[a] = (unsigned short)h;
                sG_lo[a] = (unsigned short)l;
            }
        }
        __syncthreads();
    }

    // ---- conv2 weights: waves 0,1 -> residual oc, waves 2,3 -> skip oc ----
    const int oc0 = 32 * ocg + cc;
    const int oc1 = oc0 + 16;
#pragma unroll
    for (int q = 0; q < 6; ++q) {
        const int j = q >> 1, icb = (q & 1) * 32 + kb * 8;
        const float* wp = wkT + (j * 64 + icb) * 128;
#pragma unroll
        for (int jj = 0; jj < 8; ++jj) {
            unsigned h, l;
            split2(wp[jj * 128 + oc0], h, l);
            whA[q][jj] = (short)h; wlA[q][jj] = (short)l;
            split2(wp[jj * 128 + oc1], h, l);
            whB[q][jj] = (short)h; wlB[q][jj] = (short)l;
        }
    }

    // ---- pass B: pure MFMA burst, no syncs, no staging ----
    for (int s = 0; s < NSTEP; ++s) {
        f32x4 aA = {0.f, 0.f, 0.f, 0.f}, aB = {0.f, 0.f, 0.f, 0.f};
#pragma unroll
        for (int q = 0; q < 6; ++q) {
            const int ic0 = (q & 1) * 32 + kb * 8;
            const int gc = s * 16 + cc + (q >> 1);
            const int us = gc * 64 + (ic0 ^ ((gc & 7) * 8));
            short8 ah = *(const short8*)(sG_hi + us);
            short8 al = *(const short8*)(sG_lo + us);
            aA = MFMA(ah, whA[q], aA);
            aA = MFMA(al, whA[q], aA);
            aA = MFMA(ah, wlA[q], aA);
            aB = MFMA(ah, whB[q], aB);
            aB = MFMA(al, whB[q], aB);
            aB = MFMA(ah, wlB[q], aB);
        }
        const int trow = tbase + s * 16 + kb * 4;
        if (ocg < 2) {
            size_t o0 = ((size_t)bb * 64 + oc0) * T_ + trow;
            u32x4 hv = *(const u32x4*)(hin + o0);
            u32x4 ov;
#pragma unroll
            for (int r = 0; r < 4; ++r) ov[r] = packf(unpf(hv[r]) + aA[r]);
            *(u32x4*)(hout + o0) = ov;
            size_t o1 = ((size_t)bb * 64 + oc1) * T_ + trow;
            hv = *(const u32x4*)(hin + o1);
#pragma unroll
            for (int r = 0; r < 4; ++r) ov[r] = packf(unpf(hv[r]) + aB[r]);
            *(u32x4*)(hout + o1) = ov;
        } else {
            size_t o0 = ((size_t)bb * 64 + (oc0 - 64)) * T_ + trow;
            f32x4 sv = ACC ? *(const f32x4*)(skip + o0) : (f32x4){0.f, 0.f, 0.f, 0.f};
            *(f32x4*)(skip + o0) = sv + aA;
            size_t o1 = ((size_t)bb * 64 + (oc1 - 64)) * T_ + trow;
            sv = ACC ? *(const f32x4*)(skip + o1) : (f32x4){0.f, 0.f, 0.f, 0.f};
            *(f32x4*)(skip + o1) = sv + aB;
        }
    }
}

// ---------------- post-net 64->64 conv (k=3,d=1), optional tanh in, tanh out ---
template <int INTANH>
__global__ __launch_bounds__(256)
void k_post(const float* __restrict__ in, float* __restrict__ out,
            const float* __restrict__ wT /* [3][64][64] */) {
    __shared__ __align__(16) unsigned short sHi[18 * 64];
    __shared__ __align__(16) unsigned short sLo[18 * 64];
    const int tid = threadIdx.x;
    const int lane = tid & 63;
    const int ocg = tid >> 6;
    const int cc = lane & 15;
    const int kb = lane >> 4;
    const int bb = blockIdx.y;
    const int tbase = blockIdx.x * STRIP;
    const float* ib = in + (size_t)bb * 64 * T_;

    const int oc = 16 * ocg + cc;
    short8 wh[6], wl[6];
#pragma unroll
    for (int q = 0; q < 6; ++q) {
        const int j = q >> 1, icb = (q & 1) * 32 + kb * 8;
        const float* wp = wT + (j * 64 + icb) * 64;
#pragma unroll
        for (int jj = 0; jj < 8; ++jj) {
            unsigned h, l;
            split2(wp[jj * 64 + oc], h, l);
            wh[q][jj] = (short)h; wl[q][jj] = (short)l;
        }
    }

    for (int step = 0; step < NSTEP; ++step) {
        const int t0 = tbase + step * 16;
#pragma unroll
        for (int it = 0; it < 3; ++it) {
            int idx = it * 256 + tid;
            if (idx < 576) {
                int ic2 = idx / 18;
                int c = idx - ic2 * 18;
                int t = t0 - 2 + c;
                float v0 = 0.f, v1 = 0.f;
                if (t >= 0) {
                    v0 = ib[(2 * ic2) * T_ + t];
                    v1 = ib[(2 * ic2 + 1) * T_ + t];
                }
                if (INTANH) { v0 = ftanh(v0); v1 = ftanh(v1); }
                unsigned h0, l0, h1, l1;
                split2(v0, h0, l0);
                split2(v1, h1, l1);
                int w = c * 32 + (ic2 ^ ((c & 7) * 4));
                ((unsigned*)sHi)[w] = h0 | (h1 << 16);
                ((unsigned*)sLo)[w] = l0 | (l1 << 16);
            }
        }
        __syncthreads();

        f32x4 acc = {0.f, 0.f, 0.f, 0.f};
#pragma unroll
        for (int q = 0; q < 6; ++q) {
            const int j = q >> 1;
            const int ic0 = (q & 1) * 32 + kb * 8;
            const int c = cc + j;
            const int us = c * 64 + (ic0 ^ ((c & 7) * 8));
            short8 ah = *(const short8*)(sHi + us);
            short8 al = *(const short8*)(sLo + us);
            acc = MFMA(ah, wh[q], acc);
            acc = MFMA(al, wh[q], acc);
            acc = MFMA(ah, wl[q], acc);
        }
        __syncthreads();

        const int trow = t0 + kb * 4;
        f32x4 o;
#pragma unroll
        for (int r = 0; r < 4; ++r) o[r] = ftanh(acc[r]);
        *(f32x4*)(out + ((size_t)bb * 64 + oc) * T_ + trow) = o;
    }
}

// y = tanh(cconv(in, w4)), 64 -> 1 channel
__global__ void k_last(const float* __restrict__ in, const float* __restrict__ w4,
                       float* __restrict__ y) {
    int t = blockIdx.x * 256 + threadIdx.x;
    int b = blockIdx.y;
    const float* ib = in + (size_t)b * 64 * T_;
    float acc = 0.f;
    for (int ic = 0; ic < 64; ++ic) {
        const float* r = ib + ic * T_;
        float s = w4[ic * 3 + 2] * r[t];
        if (t >= 1) s += w4[ic * 3 + 1] * r[t - 1];
        if (t >= 2) s += w4[ic * 3 + 0] * r[t - 2];
        acc += s;
    }
    y[b * T_ + t] = ftanh(acc);
}

// VNN2
__global__ void k_vnn(const float* __restrict__ y, const float* __restrict__ vw1,
                      const float* __restrict__ vw2, float* __restrict__ out) {
    int t = blockIdx.x * 256 + threadIdx.x;
    int b = blockIdx.y;
    const float* yb = y + b * T_;
    float v[5];
#pragma unroll
    for (int j = 0; j < 5; ++j) {
        int tt = t - 4 + j;
        v[j] = (tt >= 0) ? yb[tt] : 0.f;
    }
    float lin = 0.f;
#pragma unroll
    for (int j = 0; j < 5; ++j) lin += v[j] * vw1[j];
    float xa[6];
#pragma unroll
    for (int c = 0; c < 6; ++c) {
        float s = 0.f;
#pragma unroll
        for (int j = 0; j < 5; ++j) s += v[j] * vw2[c * 5 + j];
        xa[c] = s;
    }
    out[b * T_ + t] = lin + xa[0] * xa[3] + xa[1] * xa[4] + xa[2] * xa[5];
}

extern "C" void kernel_launch(void* const* d_in, const int* in_sizes, int n_in,
                              void* d_out, int out_size, void* d_ws, size_t ws_size,
                              hipStream_t stream) {
    const float* x      = (const float*)d_in[0];
    const float* w_in   = (const float*)d_in[1];
    const float* w_res  = (const float*)d_in[2];
    const float* w_skip = (const float*)d_in[3];
    const float* w2     = (const float*)d_in[4];
    const float* w3     = (const float*)d_in[5];
    const float* w4     = (const float*)d_in[6];
    const float* vw1    = (const float*)d_in[7];
    const float* vw2    = (const float*)d_in[8];

    float* ws = (float*)d_ws;
    const size_t HSZ = (size_t)B_ * 64 * T_;     // 16,384,000
    unsigned* hA     = (unsigned*)ws;
    unsigned* hB     = hA + HSZ;
    float*    skip   = (float*)(hB + HSZ);
    float*    y      = skip + HSZ;
    float*    wresT  = y + (size_t)B_ * T_;
    float*    wskipT = wresT + 10 * 3 * 64 * 128;
    float*    w2T    = wskipT + 10 * 3 * 64 * 128;
    float*    w3T    = w2T + 3 * 64 * 64;

    k_tr<<<dim3(960), 256, 0, stream>>>(w_res, wresT, 10, 128, 64);
    k_tr<<<dim3(960), 256, 0, stream>>>(w_skip, wskipT, 10, 128, 64);
    k_tr<<<dim3(48), 256, 0, stream>>>(w2, w2T, 1, 64, 64);
    k_tr<<<dim3(48), 256, 0, stream>>>(w3, w3T, 1, 64, 64);

    k_in<<<dim3(T_ / 256, 64, B_), 256, 0, stream>>>(x, w_in, hA);

    unsigned* cur = hA;
    unsigned* nxt = hB;
    for (int li = 0; li < 20; ++li) {
        int i = li % 10;
        int d = 1 << i;
        const float* wr = wresT + i * 3 * 64 * 128;
        const float* wk = wskipT + i * 3 * 64 * 128;
        if (li == 0)
            k_layer<0><<<dim3(NSTRIP, B_), 256, 0, stream>>>(cur, nxt, skip, wr, wk, d);
        else
            k_layer<1><<<dim3(NSTRIP, B_), 256, 0, stream>>>(cur, nxt, skip, wr, wk, d);
        unsigned* tmp = cur; cur = nxt; nxt = tmp;
    }

    // post-net: tanh(skip) -> conv w2 (tanh) -> conv w3 (tanh) -> w4 (tanh) -> VNN
    k_post<1><<<dim3(NSTRIP, B_), 256, 0, stream>>>(skip, (float*)hB, w2T);
    k_post<0><<<dim3(NSTRIP, B_), 256, 0, stream>>>((float*)hB, (float*)hA, w3T);
    k_last<<<dim3(T_ / 256, B_), 256, 0, stream>>>((float*)hA, w4, y);
    k_vnn<<<dim3(T_ / 256, B_), 256, 0, stream>>>(y, vw1, vw2, (float*)d_out);
}

// Round 4
// 2645.578 us; speedup vs baseline: 4.1782x; 1.1293x over previous
//
#include <hip/hip_runtime.h>

#define B_ 8
#define T_ 32000
#define NSTEP 16
#define STRIP 256
#define NSTRIP 125

typedef __attribute__((ext_vector_type(8))) _Float16 half8;
typedef __attribute__((ext_vector_type(4))) float f32x4;
typedef __attribute__((ext_vector_type(4))) unsigned u32x4;

#define MFMA(a, b, c) __builtin_amdgcn_mfma_f32_16x16x32_f16(a, b, c, 0, 0, 0)

__device__ __forceinline__ float ftanh(float x) {
    return 1.0f - 2.0f / (1.0f + __expf(2.0f * x));
}
__device__ __forceinline__ float fsig(float x) {
    return 1.0f / (1.0f + __expf(-x));
}
__device__ __forceinline__ unsigned short f2h(float x) {
    _Float16 h = (_Float16)x;
    return __builtin_bit_cast(unsigned short, h);
}
__device__ __forceinline__ float h2f(unsigned short u) {
    return (float)__builtin_bit_cast(_Float16, u);
}
// pack float as fp16 hi/lo pair in u32 (lo16 = main, hi16 = residual)
__device__ __forceinline__ unsigned packh(float x) {
    unsigned short hh = f2h(x);
    unsigned short hl = f2h(x - h2f(hh));
    return (unsigned)hh | ((unsigned)hl << 16);
}
__device__ __forceinline__ float unph(unsigned v) {
    return h2f((unsigned short)(v & 0xffffu)) + h2f((unsigned short)(v >> 16));
}

// transpose [L][OC][IC][3] -> [L][3][IC][OC]
__global__ void k_tr(const float* __restrict__ src, float* __restrict__ dst,
                     int L, int OC, int IC) {
    int n = L * OC * IC * 3;
    int idx = blockIdx.x * 256 + threadIdx.x;
    if (idx >= n) return;
    int j = idx % 3;
    int ic = (idx / 3) % IC;
    int oc = (idx / (3 * IC)) % OC;
    int l = idx / (3 * IC * OC);
    dst[((l * 3 + j) * IC + ic) * OC + oc] = src[idx];
}

// h = cconv(x, w_in) -> packed fp16-pair u32
__global__ void k_in(const float* __restrict__ x, const float* __restrict__ w_in,
                     unsigned* __restrict__ h) {
    int t = blockIdx.x * 256 + threadIdx.x;
    int c = blockIdx.y, b = blockIdx.z;
    const float* xb = x + b * T_;
    float w0 = w_in[c * 3], w1 = w_in[c * 3 + 1], w2 = w_in[c * 3 + 2];
    float acc = w2 * xb[t];
    if (t >= 1) acc += w1 * xb[t - 1];
    if (t >= 2) acc += w0 * xb[t - 2];
    h[(b * 64 + c) * T_ + t] = packh(acc);
}

// ---------------- fused residual layer (two-pass over a 256-col strip) --------
// pass A: g = cconv_d(h, wres); gated = tanh*sig -> sG fp16 (258 cols, 2 halo)
// pass B: o = cconv_1(gated, wskip); hout = hin + o[:64] (packed); skip += o[64:]
template <int ACC>
__global__ __launch_bounds__(256, 3)
void k_layer(const unsigned* __restrict__ hin, unsigned* __restrict__ hout,
             float* __restrict__ skip,
             const float* __restrict__ wrT,   // [3][64][128]
             const float* __restrict__ wkT,   // [3][64][128]
             int d) {
    __shared__ __align__(16) unsigned sH_hi[3 * 512];        // [j][c16][icp32 swz]
    __shared__ __align__(16) unsigned sH_lo[3 * 512];
    __shared__ __align__(16) unsigned short sG[258 * 64];    // fp16 bits [gc][ic swz]

    const int tid = threadIdx.x;
    const int lane = tid & 63;
    const int ocg = tid >> 6;        // 0..3
    const int cc = lane & 15;
    const int kb = lane >> 4;        // 0..3
    const int bb = blockIdx.x & 7;           // XCD-aware: one batch per XCD
    const int tbase = (blockIdx.x >> 3) * STRIP;
    const unsigned* hb = hin + (size_t)bb * 64 * T_;

    half8 whA[6], wlA[6], whB[6], wlB[6];

    // ---- conv1 weights (fp16 split-2): g-channels cA (tanh), cA+64 (sig) ----
    {
        const int cA = 16 * ocg + cc, cB = cA + 64;
#pragma unroll
        for (int q = 0; q < 6; ++q) {
            const int j = q >> 1, icb = (q & 1) * 32 + kb * 8;
            const float* wp = wrT + (j * 64 + icb) * 128;
#pragma unroll
            for (int jj = 0; jj < 8; ++jj) {
                float wa = wp[jj * 128 + cA];
                _Float16 wh = (_Float16)wa;
                whA[q][jj] = wh;
                wlA[q][jj] = (_Float16)(wa - (float)wh);
                float wb = wp[jj * 128 + cB];
                wh = (_Float16)wb;
                whB[q][jj] = wh;
                wlB[q][jj] = (_Float16)(wb - (float)wh);
            }
        }
    }

    // ---- pass A: 17 steps (step -1 fills the 2-col halo) ----
    for (int s = -1; s < NSTEP; ++s) {
        const int t0 = tbase + s * 16;
#pragma unroll
        for (int it = 0; it < 6; ++it) {
            int idx = it * 256 + tid;          // < 1536
            int j = idx >> 9;
            int r = idx & 511;
            int icp = r >> 4;                  // channel pair 0..31
            int c = r & 15;
            int t = t0 + c - d * (2 - j);
            unsigned v0 = 0u, v1 = 0u;
            if (t >= 0) {
                v0 = hb[(2 * icp) * T_ + t];
                v1 = hb[(2 * icp + 1) * T_ + t];
            }
            int w = j * 512 + c * 32 + (icp ^ ((c & 7) * 4));
            sH_hi[w] = (v0 & 0xffffu) | (v1 << 16);
            sH_lo[w] = (v0 >> 16) | (v1 & 0xffff0000u);
        }
        __syncthreads();

        f32x4 accA = {0.f, 0.f, 0.f, 0.f}, accB = {0.f, 0.f, 0.f, 0.f};
#pragma unroll
        for (int q = 0; q < 6; ++q) {
            const int j = q >> 1;
            const int ic0 = (q & 1) * 32 + kb * 8;
            const int us = j * 1024 + cc * 64 + (ic0 ^ ((cc & 7) * 8));
            half8 ah = *(const half8*)((const unsigned short*)sH_hi + us);
            half8 al = *(const half8*)((const unsigned short*)sH_lo + us);
            accA = MFMA(ah, whA[q], accA);
            accA = MFMA(al, whA[q], accA);
            accA = MFMA(ah, wlA[q], accA);
            accB = MFMA(ah, whB[q], accB);
            accB = MFMA(al, whB[q], accB);
            accB = MFMA(ah, wlB[q], accB);
        }

        // gate + write fp16 into persistent gated tile
        const int cA = 16 * ocg + cc;
#pragma unroll
        for (int r = 0; r < 4; ++r) {
            int gc = s * 16 + kb * 4 + r + 2;
            if (gc >= 0) {
                float gv = ftanh(accA[r]) * fsig(accB[r]);
                sG[gc * 64 + (cA ^ ((gc & 7) * 8))] = f2h(gv);
            }
        }
        __syncthreads();
    }

    // ---- conv2 weights: waves 0,1 -> residual oc, waves 2,3 -> skip oc ----
    const int oc0 = 32 * ocg + cc;
    const int oc1 = oc0 + 16;
#pragma unroll
    for (int q = 0; q < 6; ++q) {
        const int j = q >> 1, icb = (q & 1) * 32 + kb * 8;
        const float* wp = wkT + (j * 64 + icb) * 128;
#pragma unroll
        for (int jj = 0; jj < 8; ++jj) {
            float wa = wp[jj * 128 + oc0];
            _Float16 wh = (_Float16)wa;
            whA[q][jj] = wh;
            wlA[q][jj] = (_Float16)(wa - (float)wh);
            float wb = wp[jj * 128 + oc1];
            wh = (_Float16)wb;
            whB[q][jj] = wh;
            wlB[q][jj] = (_Float16)(wb - (float)wh);
        }
    }

    // ---- pass B: pure MFMA burst (A-operand exact fp16 -> 2-term) ----
    for (int s = 0; s < NSTEP; ++s) {
        f32x4 aA = {0.f, 0.f, 0.f, 0.f}, aB = {0.f, 0.f, 0.f, 0.f};
#pragma unroll
        for (int q = 0; q < 6; ++q) {
            const int ic0 = (q & 1) * 32 + kb * 8;
            const int gc = s * 16 + cc + (q >> 1);
            const int us = gc * 64 + (ic0 ^ ((gc & 7) * 8));
            half8 a = *(const half8*)(sG + us);
            aA = MFMA(a, whA[q], aA);
            aA = MFMA(a, wlA[q], aA);
            aB = MFMA(a, whB[q], aB);
            aB = MFMA(a, wlB[q], aB);
        }
        const int trow = tbase + s * 16 + kb * 4;
        if (ocg < 2) {
            size_t o0 = ((size_t)bb * 64 + oc0) * T_ + trow;
            u32x4 hv = *(const u32x4*)(hin + o0);
            u32x4 ov;
#pragma unroll
            for (int r = 0; r < 4; ++r) ov[r] = packh(unph(hv[r]) + aA[r]);
            *(u32x4*)(hout + o0) = ov;
            size_t o1 = ((size_t)bb * 64 + oc1) * T_ + trow;
            hv = *(const u32x4*)(hin + o1);
#pragma unroll
            for (int r = 0; r < 4; ++r) ov[r] = packh(unph(hv[r]) + aB[r]);
            *(u32x4*)(hout + o1) = ov;
        } else {
            size_t o0 = ((size_t)bb * 64 + (oc0 - 64)) * T_ + trow;
            f32x4 sv = ACC ? *(const f32x4*)(skip + o0) : (f32x4){0.f, 0.f, 0.f, 0.f};
            *(f32x4*)(skip + o0) = sv + aA;
            size_t o1 = ((size_t)bb * 64 + (oc1 - 64)) * T_ + trow;
            sv = ACC ? *(const f32x4*)(skip + o1) : (f32x4){0.f, 0.f, 0.f, 0.f};
            *(f32x4*)(skip + o1) = sv + aB;
        }
    }
}

// ---------------- post-net 64->64 conv (k=3,d=1), optional tanh in, tanh out ---
template <int INTANH>
__global__ __launch_bounds__(256)
void k_post(const float* __restrict__ in, float* __restrict__ out,
            const float* __restrict__ wT /* [3][64][64] */) {
    __shared__ __align__(16) unsigned sHi[(18 * 64) / 2];
    __shared__ __align__(16) unsigned sLo[(18 * 64) / 2];
    const int tid = threadIdx.x;
    const int lane = tid & 63;
    const int ocg = tid >> 6;
    const int cc = lane & 15;
    const int kb = lane >> 4;
    const int bb = blockIdx.y;
    const int tbase = blockIdx.x * STRIP;
    const float* ib = in + (size_t)bb * 64 * T_;

    const int oc = 16 * ocg + cc;
    half8 wh[6], wl[6];
#pragma unroll
    for (int q = 0; q < 6; ++q) {
        const int j = q >> 1, icb = (q & 1) * 32 + kb * 8;
        const float* wp = wT + (j * 64 + icb) * 64;
#pragma unroll
        for (int jj = 0; jj < 8; ++jj) {
            float wv = wp[jj * 64 + oc];
            _Float16 h = (_Float16)wv;
            wh[q][jj] = h;
            wl[q][jj] = (_Float16)(wv - (float)h);
        }
    }

    for (int step = 0; step < NSTEP; ++step) {
        const int t0 = tbase + step * 16;
#pragma unroll
        for (int it = 0; it < 3; ++it) {
            int idx = it * 256 + tid;
            if (idx < 576) {
                int ic2 = idx / 18;
                int c = idx - ic2 * 18;
                int t = t0 - 2 + c;
                float v0 = 0.f, v1 = 0.f;
                if (t >= 0 && t < T_) {
                    v0 = ib[(2 * ic2) * T_ + t];
                    v1 = ib[(2 * ic2 + 1) * T_ + t];
                }
                if (INTANH) { v0 = ftanh(v0); v1 = ftanh(v1); }
                unsigned short h0 = f2h(v0), h1 = f2h(v1);
                unsigned short l0 = f2h(v0 - h2f(h0)), l1 = f2h(v1 - h2f(h1));
                int w = c * 32 + (ic2 ^ ((c & 7) * 4));
                sHi[w] = (unsigned)h0 | ((unsigned)h1 << 16);
                sLo[w] = (unsigned)l0 | ((unsigned)l1 << 16);
            }
        }
        __syncthreads();

        f32x4 acc = {0.f, 0.f, 0.f, 0.f};
#pragma unroll
        for (int q = 0; q < 6; ++q) {
            const int j = q >> 1;
            const int ic0 = (q & 1) * 32 + kb * 8;
            const int c = cc + j;
            const int us = c * 64 + (ic0 ^ ((c & 7) * 8));
            half8 ah = *(const half8*)((const unsigned short*)sHi + us);
            half8 al = *(const half8*)((const unsigned short*)sLo + us);
            acc = MFMA(ah, wh[q], acc);
            acc = MFMA(al, wh[q], acc);
            acc = MFMA(ah, wl[q], acc);
        }
        __syncthreads();

        const int trow = t0 + kb * 4;
        f32x4 o;
#pragma unroll
        for (int r = 0; r < 4; ++r) o[r] = ftanh(acc[r]);
        *(f32x4*)(out + ((size_t)bb * 64 + oc) * T_ + trow) = o;
    }
}

// y = tanh(cconv(in, w4)), 64 -> 1 channel
__global__ void k_last(const float* __restrict__ in, const float* __restrict__ w4,
                       float* __restrict__ y) {
    int t = blockIdx.x * 256 + threadIdx.x;
    int b = blockIdx.y;
    const float* ib = in + (size_t)b * 64 * T_;
    float acc = 0.f;
    for (int ic = 0; ic < 64; ++ic) {
        const float* r = ib + ic * T_;
        float s = w4[ic * 3 + 2] * r[t];
        if (t >= 1) s += w4[ic * 3 + 1] * r[t - 1];
        if (t >= 2) s += w4[ic * 3 + 0] * r[t - 2];
        acc += s;
    }
    y[b * T_ + t] = ftanh(acc);
}

// VNN2
__global__ void k_vnn(const float* __restrict__ y, const float* __restrict__ vw1,
                      const float* __restrict__ vw2, float* __restrict__ out) {
    int t = blockIdx.x * 256 + threadIdx.x;
    int b = blockIdx.y;
    const float* yb = y + b * T_;
    float v[5];
#pragma unroll
    for (int j = 0; j < 5; ++j) {
        int tt = t - 4 + j;
        v[j] = (tt >= 0) ? yb[tt] : 0.f;
    }
    float lin = 0.f;
#pragma unroll
    for (int j = 0; j < 5; ++j) lin += v[j] * vw1[j];
    float xa[6];
#pragma unroll
    for (int c = 0; c < 6; ++c) {
        float s = 0.f;
#pragma unroll
        for (int j = 0; j < 5; ++j) s += v[j] * vw2[c * 5 + j];
        xa[c] = s;
    }
    out[b * T_ + t] = lin + xa[0] * xa[3] + xa[1] * xa[4] + xa[2] * xa[5];
}

extern "C" void kernel_launch(void* const* d_in, const int* in_sizes, int n_in,
                              void* d_out, int out_size, void* d_ws, size_t ws_size,
                              hipStream_t stream) {
    const float* x      = (const float*)d_in[0];
    const float* w_in   = (const float*)d_in[1];
    const float* w_res  = (const float*)d_in[2];
    const float* w_skip = (const float*)d_in[3];
    const float* w2     = (const float*)d_in[4];
    const float* w3     = (const float*)d_in[5];
    const float* w4     = (const float*)d_in[6];
    const float* vw1    = (const float*)d_in[7];
    const float* vw2    = (const float*)d_in[8];

    float* ws = (float*)d_ws;
    const size_t HSZ = (size_t)B_ * 64 * T_;     // 16,384,000
    unsigned* hA     = (unsigned*)ws;
    unsigned* hB     = hA + HSZ;
    float*    skip   = (float*)(hB + HSZ);
    float*    y      = skip + HSZ;
    float*    wresT  = y + (size_t)B_ * T_;
    float*    wskipT = wresT + 10 * 3 * 64 * 128;
    float*    w2T    = wskipT + 10 * 3 * 64 * 128;
    float*    w3T    = w2T + 3 * 64 * 64;

    k_tr<<<dim3(960), 256, 0, stream>>>(w_res, wresT, 10, 128, 64);
    k_tr<<<dim3(960), 256, 0, stream>>>(w_skip, wskipT, 10, 128, 64);
    k_tr<<<dim3(48), 256, 0, stream>>>(w2, w2T, 1, 64, 64);
    k_tr<<<dim3(48), 256, 0, stream>>>(w3, w3T, 1, 64, 64);

    k_in<<<dim3(T_ / 256, 64, B_), 256, 0, stream>>>(x, w_in, hA);

    unsigned* cur = hA;
    unsigned* nxt = hB;
    for (int li = 0; li < 20; ++li) {
        int i = li % 10;
        int d = 1 << i;
        const float* wr = wresT + i * 3 * 64 * 128;
        const float* wk = wskipT + i * 3 * 64 * 128;
        if (li == 0)
            k_layer<0><<<dim3(NSTRIP * B_), 256, 0, stream>>>(cur, nxt, skip, wr, wk, d);
        else
            k_layer<1><<<dim3(NSTRIP * B_), 256, 0, stream>>>(cur, nxt, skip, wr, wk, d);
        unsigned* tmp = cur; cur = nxt; nxt = tmp;
    }

    // post-net: tanh(skip) -> conv w2 (tanh) -> conv w3 (tanh) -> w4 (tanh) -> VNN
    k_post<1><<<dim3(NSTRIP, B_), 256, 0, stream>>>(skip, (float*)hB, w2T);
    k_post<0><<<dim3(NSTRIP, B_), 256, 0, stream>>>((float*)hB, (float*)hA, w3T);
    k_last<<<dim3(T_ / 256, B_), 256, 0, stream>>>((float*)hA, w4, y);
    k_vnn<<<dim3(T_ / 256, B_), 256, 0, stream>>>(y, vw1, vw2, (float*)d_out);
}